// Round 4
// baseline (276.485 us; speedup 1.0000x reference)
//
#include <hip/hip_runtime.h>

typedef unsigned short u16;
typedef unsigned int   u32;
typedef __attribute__((ext_vector_type(4))) float  f32x4;
typedef __attribute__((ext_vector_type(8))) __bf16 bf16x8;

#define RPB   512            // rows per block: 4 waves x 32 rows x 4 iters
#define ITERS 4
#define SMEM_BYTES 74496     // 6*8KB wf3 + 8KB wf2 + 16KB wb + 768B bias -> 2 blocks/CU

__device__ __forceinline__ u32 pkbf(float a, float b){
  u16 ua = __builtin_bit_cast(u16, (__bf16)a);
  u16 ub = __builtin_bit_cast(u16, (__bf16)b);
  return (u32)ua | ((u32)ub << 16);
}
__device__ __forceinline__ u32 pk2(__bf16 a, __bf16 b){
  return (u32)__builtin_bit_cast(u16, a) | ((u32)__builtin_bit_cast(u16, b) << 16);
}
__device__ __forceinline__ bf16x8 ldfrag(const u16* base, int idx){
  return __builtin_bit_cast(bf16x8, *(const uint4*)(base + (size_t)idx * 8));
}
__device__ __forceinline__ bf16x8 cvt8(float4 a, float4 b){
  uint4 u;
  u.x = pkbf(a.x, a.y); u.y = pkbf(a.z, a.w);
  u.z = pkbf(b.x, b.y); u.w = pkbf(b.z, b.w);
  return __builtin_bit_cast(bf16x8, u);
}
__device__ __forceinline__ f32x4 mfma16(bf16x8 a, bf16x8 b, f32x4 c){
  return __builtin_amdgcn_mfma_f32_16x16x32_bf16(a, b, c, 0, 0, 0);
}
// exact 3-way bf16 split of 8 f32
__device__ __forceinline__ void split8(float4 a, float4 b, bf16x8* out){
  float x[8] = {a.x, a.y, a.z, a.w, b.x, b.y, b.z, b.w};
  bf16x8 l0, l1, l2;
  #pragma unroll
  for (int j = 0; j < 8; ++j){
    float v = x[j];
    __bf16 p0 = (__bf16)v; float r = v - (float)p0;
    __bf16 p1 = (__bf16)r; r = r - (float)p1;
    __bf16 p2 = (__bf16)r;
    l0[j] = p0; l1[j] = p1; l2[j] = p2;
  }
  out[0] = l0; out[1] = l1; out[2] = l2;
}
__device__ __forceinline__ float4 shflf4(f32x4 v, int src){
  float4 r;
  r.x = __shfl(v[0], src, 64); r.y = __shfl(v[1], src, 64);
  r.z = __shfl(v[2], src, 64); r.w = __shfl(v[3], src, 64);
  return r;
}
__device__ __forceinline__ uint2 shflu2(uint2 v, int src){
  uint2 r;
  r.x = (u32)__shfl((int)v.x, src, 64);
  r.y = (u32)__shfl((int)v.y, src, 64);
  return r;
}
// C-layout (4 f32x4 tiles) -> B-frags (3-level split), intra-wave, no LDS/barrier.
// Dest lane (n,q): B0 = tile(q>>1) regs from lanes n+16*(2(q&1)), n+16*(2(q&1)+1); B1 = tile(2+(q>>1)) same srcs.
__device__ __forceinline__ void xpose_f32(const f32x4 h[4], int srcA, int srcB, bool hi,
                                          bf16x8* B0, bf16x8* B1){
  float4 Fa0 = shflf4(h[0], srcA), Fb0 = shflf4(h[0], srcB);
  float4 Fa1 = shflf4(h[1], srcA), Fb1 = shflf4(h[1], srcB);
  float4 Fa2 = shflf4(h[2], srcA), Fb2 = shflf4(h[2], srcB);
  float4 Fa3 = shflf4(h[3], srcA), Fb3 = shflf4(h[3], srcB);
  float4 lo0 = hi ? Fa1 : Fa0, hi0 = hi ? Fb1 : Fb0;
  float4 lo1 = hi ? Fa3 : Fa2, hi1 = hi ? Fb3 : Fb2;
  split8(lo0, hi0, B0);
  split8(lo1, hi1, B1);
}
__device__ __forceinline__ void xpose_bf(const uint2 p[4], int srcA, int srcB, bool hi,
                                         bf16x8* B0, bf16x8* B1){
  uint2 Pa0 = shflu2(p[0], srcA), Pb0 = shflu2(p[0], srcB);
  uint2 Pa1 = shflu2(p[1], srcA), Pb1 = shflu2(p[1], srcB);
  uint2 Pa2 = shflu2(p[2], srcA), Pb2 = shflu2(p[2], srcB);
  uint2 Pa3 = shflu2(p[3], srcA), Pb3 = shflu2(p[3], srcB);
  uint2 a0 = hi ? Pa1 : Pa0, b0 = hi ? Pb1 : Pb0;
  uint2 a1 = hi ? Pa3 : Pa2, b1 = hi ? Pb3 : Pb2;
  uint4 u0; u0.x = a0.x; u0.y = a0.y; u0.z = b0.x; u0.w = b0.y;
  uint4 u1; u1.x = a1.x; u1.y = a1.y; u1.z = b1.x; u1.w = b1.y;
  *B0 = __builtin_bit_cast(bf16x8, u0);
  *B1 = __builtin_bit_cast(bf16x8, u1);
}
// hp layer: 3-level A (LDS) x 3-level B (regs), 6 significant terms, 2 col-sets share A-frags
__device__ __forceinline__ void hp_layer(const u16* w0, const u16* w1, const u16* w2,
    int lane, const bf16x8 Bv[2][2][3], f32x4 hout[2][4]){
  #pragma unroll
  for (int mt = 0; mt < 4; ++mt){
    const int f0 = (mt*2+0)*64 + lane, f1 = (mt*2+1)*64 + lane;
    bf16x8 A00 = ldfrag(w0, f0), A01 = ldfrag(w1, f0), A02 = ldfrag(w2, f0);
    bf16x8 A10 = ldfrag(w0, f1), A11 = ldfrag(w1, f1), A12 = ldfrag(w2, f1);
    #pragma unroll
    for (int c = 0; c < 2; ++c){
      f32x4 a = {0.f, 0.f, 0.f, 0.f};
      a = mfma16(A00, Bv[c][0][0], a);
      a = mfma16(A00, Bv[c][0][1], a);
      a = mfma16(A01, Bv[c][0][0], a);
      a = mfma16(A00, Bv[c][0][2], a);
      a = mfma16(A01, Bv[c][0][1], a);
      a = mfma16(A02, Bv[c][0][0], a);
      a = mfma16(A10, Bv[c][1][0], a);
      a = mfma16(A10, Bv[c][1][1], a);
      a = mfma16(A11, Bv[c][1][0], a);
      a = mfma16(A10, Bv[c][1][2], a);
      a = mfma16(A11, Bv[c][1][1], a);
      a = mfma16(A12, Bv[c][1][0], a);
      hout[c][mt] = a;
    }
  }
}

// M = feature dim (A = weights, LDS), N = batch (B = activations).
// A: A[m=lane&15][k=(lane>>4)*8+j]; C/D: n=lane&15, m=(lane>>4)*4+r.
__global__ __launch_bounds__(256, 2) void ode_fused(
    const float* __restrict__ tptr, const float* __restrict__ z, const float* __restrict__ e,
    const float* __restrict__ W0p, const float* __restrict__ b0p,
    const float* __restrict__ W1p, const float* __restrict__ b1p,
    const float* __restrict__ W2p, const float* __restrict__ b2p,
    float* __restrict__ out, long long Btot)
{
  extern __shared__ __align__(16) char smem[];
  u16*   wf3  = (u16*)smem;                 // [6][4096] fwd L0/L1 A-frags, 3 levels each
  u16*   wf2  = wf3 + 6*4096;               // [4096] fwd L2 A-frags
  u16*   wb   = wf2 + 4096;                 // [2][4096]: W1^T, W2^T bwd A-frags
  float* bias = (float*)(wb + 2*4096);      // [3][64]

  const int tid = threadIdx.x;
  const float tf = tptr[0];
  const float* Ws[3] = {W0p, W1p, W2p};
  const float* bs[3] = {b0p, b1p, b2p};

  // ---- one-time weight staging ----
  for (int L = 0; L < 3; ++L){
    const float* W = Ws[L];
    for (int eidx = tid; eidx < 512; eidx += 256){
      const int l = eidx & 63, km = eidx >> 6;
      const int mt = km >> 1, kc = km & 1;
      const int n15 = l & 15, q = l >> 4;
      { // forward A[m][k] = W[m][k+1]
        const float* p = W + (mt*16 + n15)*65 + 1 + kc*32 + q*8;
        if (L < 2){
          uint4 u0, u1, u2;
          u32* d0 = (u32*)&u0; u32* d1 = (u32*)&u1; u32* d2 = (u32*)&u2;
          #pragma unroll
          for (int h = 0; h < 4; ++h){
            __bf16 a0, a1, a2, c0, c1, c2;
            float v = p[2*h];
            a0 = (__bf16)v; float r = v - (float)a0;
            a1 = (__bf16)r; r = r - (float)a1; a2 = (__bf16)r;
            v = p[2*h+1];
            c0 = (__bf16)v; r = v - (float)c0;
            c1 = (__bf16)r; r = r - (float)c1; c2 = (__bf16)r;
            d0[h] = pk2(a0, c0); d1[h] = pk2(a1, c1); d2[h] = pk2(a2, c2);
          }
          *(uint4*)(&wf3[(L*3+0)*4096 + eidx*8]) = u0;
          *(uint4*)(&wf3[(L*3+1)*4096 + eidx*8]) = u1;
          *(uint4*)(&wf3[(L*3+2)*4096 + eidx*8]) = u2;
        } else {
          uint4 u;
          u.x = pkbf(p[0], p[1]); u.y = pkbf(p[2], p[3]);
          u.z = pkbf(p[4], p[5]); u.w = pkbf(p[6], p[7]);
          *(uint4*)(&wf2[eidx*8]) = u;
        }
      }
      if (L >= 1){ // backward A[m][k] = W[k][m+1]
        const float* p = W + (kc*32 + q*8)*65 + mt*16 + n15 + 1;
        uint4 u;
        u.x = pkbf(p[0],   p[65]);  u.y = pkbf(p[130], p[195]);
        u.z = pkbf(p[260], p[325]); u.w = pkbf(p[390], p[455]);
        *(uint4*)(&wb[(L-1)*4096 + eidx*8]) = u;
      }
    }
  }
  if (tid < 192){
    const int L = tid >> 6, m = tid & 63;
    bias[L*64 + m] = bs[L][m] + tf * Ws[L][m*65];
  }
  __syncthreads();   // the only barrier

  const int wave = tid >> 6, lane = tid & 63;
  const int n = lane & 15, q = lane >> 4;
  const int srcA = n + 16*(2*(q & 1));
  const int srcB = srcA + 16;
  const bool hi = (q & 2) != 0;

  for (int it = 0; it < ITERS; ++it){
    const int r0 = blockIdx.x*RPB + (it*4 + wave)*32;
    const size_t row0 = (size_t)(r0 + n);
    const size_t row1 = (size_t)(r0 + 16 + n);

    // ---- load + split z for both col-sets ----
    bf16x8 zB[2][2][3];
    {
      const float4* zr = (const float4*)(z + row0*64);
      split8(zr[2*q], zr[2*q+1], &zB[0][0][0]);
      split8(zr[8+2*q], zr[9+2*q], &zB[0][1][0]);
      const float4* zr1 = (const float4*)(z + row1*64);
      split8(zr1[2*q], zr1[2*q+1], &zB[1][0][0]);
      split8(zr1[8+2*q], zr1[9+2*q], &zB[1][1][0]);
    }

    // ---- L0 (hp) ----
    f32x4 h0[2][4];
    hp_layer(wf3 + 0*4096, wf3 + 1*4096, wf3 + 2*4096, lane, zB, h0);
    #pragma unroll
    for (int c = 0; c < 2; ++c)
      #pragma unroll
      for (int mt = 0; mt < 4; ++mt){
        const f32x4 bv = *(const f32x4*)(&bias[0*64 + mt*16 + q*4]);
        #pragma unroll
        for (int r = 0; r < 4; ++r){
          float v = h0[c][mt][r] + bv[r];
          h0[c][mt][r] = v > 0.f ? v : 0.f;
        }
      }
    bf16x8 h0B[2][2][3];
    xpose_f32(h0[0], srcA, srcB, hi, &h0B[0][0][0], &h0B[0][1][0]);
    xpose_f32(h0[1], srcA, srcB, hi, &h0B[1][0][0], &h0B[1][1][0]);

    // ---- L1 (hp) ----
    f32x4 h1[2][4];
    hp_layer(wf3 + 3*4096, wf3 + 4*4096, wf3 + 5*4096, lane, h0B, h1);
    uint2 ph[2][4];
    #pragma unroll
    for (int c = 0; c < 2; ++c)
      #pragma unroll
      for (int mt = 0; mt < 4; ++mt){
        const f32x4 bv = *(const f32x4*)(&bias[1*64 + mt*16 + q*4]);
        #pragma unroll
        for (int r = 0; r < 4; ++r){
          float v = h1[c][mt][r] + bv[r];
          h1[c][mt][r] = v > 0.f ? v : 0.f;
        }
        ph[c][mt].x = pkbf(h1[c][mt][0], h1[c][mt][1]);
        ph[c][mt].y = pkbf(h1[c][mt][2], h1[c][mt][3]);
      }
    bf16x8 h1B[2][2];
    xpose_bf(ph[0], srcA, srcB, hi, &h1B[0][0], &h1B[0][1]);
    xpose_bf(ph[1], srcA, srcB, hi, &h1B[1][0], &h1B[1][1]);

    // ---- L2 + store z_dot ----
    #pragma unroll
    for (int mt = 0; mt < 4; ++mt){
      bf16x8 A0 = ldfrag(wf2, (mt*2+0)*64 + lane);
      bf16x8 A1 = ldfrag(wf2, (mt*2+1)*64 + lane);
      const f32x4 bv = *(const f32x4*)(&bias[2*64 + mt*16 + q*4]);
      #pragma unroll
      for (int c = 0; c < 2; ++c){
        f32x4 a = {0.f, 0.f, 0.f, 0.f};
        a = mfma16(A0, h1B[c][0], a);
        a = mfma16(A1, h1B[c][1], a);
        float4 w;
        w.x = a[0] + bv[0]; w.y = a[1] + bv[1];
        w.z = a[2] + bv[2]; w.w = a[3] + bv[3];
        const size_t rr = (c == 0) ? row0 : row1;
        *(float4*)(out + rr*64 + mt*16 + q*4) = w;
      }
    }

    // ---- backward ----
    bf16x8 eB[2][2];
    {
      const float4* er = (const float4*)(e + row0*64);
      eB[0][0] = cvt8(er[2*q], er[2*q+1]);
      eB[0][1] = cvt8(er[8+2*q], er[9+2*q]);
      const float4* er1 = (const float4*)(e + row1*64);
      eB[1][0] = cvt8(er1[2*q], er1[2*q+1]);
      eB[1][1] = cvt8(er1[8+2*q], er1[9+2*q]);
    }

    // g1 = (W2[:,1:]^T e) . mask1, packed for transpose
    uint2 pg[2][4];
    #pragma unroll
    for (int mt = 0; mt < 4; ++mt){
      bf16x8 A0 = ldfrag(wb + 4096, (mt*2+0)*64 + lane);
      bf16x8 A1 = ldfrag(wb + 4096, (mt*2+1)*64 + lane);
      #pragma unroll
      for (int c = 0; c < 2; ++c){
        f32x4 a = {0.f, 0.f, 0.f, 0.f};
        a = mfma16(A0, eB[c][0], a);
        a = mfma16(A1, eB[c][1], a);
        float v0 = h1[c][mt][0] > 0.f ? a[0] : 0.f;
        float v1 = h1[c][mt][1] > 0.f ? a[1] : 0.f;
        float v2 = h1[c][mt][2] > 0.f ? a[2] : 0.f;
        float v3 = h1[c][mt][3] > 0.f ? a[3] : 0.f;
        pg[c][mt].x = pkbf(v0, v1);
        pg[c][mt].y = pkbf(v2, v3);
      }
    }
    bf16x8 g1B[2][2];
    xpose_bf(pg[0], srcA, srcB, hi, &g1B[0][0], &g1B[0][1]);
    xpose_bf(pg[1], srcA, srcB, hi, &g1B[1][0], &g1B[1][1]);

    // g0 = (W1[:,1:]^T g1) . mask0 ; u = W0[:,1:] e ; div = sum(g0*u)
    float s0a = 0.f, s1a = 0.f;
    #pragma unroll
    for (int mt = 0; mt < 4; ++mt){
      bf16x8 G0 = ldfrag(wb, (mt*2+0)*64 + lane);
      bf16x8 G1 = ldfrag(wb, (mt*2+1)*64 + lane);
      bf16x8 U0 = ldfrag(wf3, (mt*2+0)*64 + lane);
      bf16x8 U1 = ldfrag(wf3, (mt*2+1)*64 + lane);
      #pragma unroll
      for (int c = 0; c < 2; ++c){
        f32x4 g = {0.f, 0.f, 0.f, 0.f};
        g = mfma16(G0, g1B[c][0], g);
        g = mfma16(G1, g1B[c][1], g);
        f32x4 u = {0.f, 0.f, 0.f, 0.f};
        u = mfma16(U0, eB[c][0], u);
        u = mfma16(U1, eB[c][1], u);
        float acc = 0.f;
        #pragma unroll
        for (int r = 0; r < 4; ++r)
          acc += (h0[c][mt][r] > 0.f) ? g[r]*u[r] : 0.f;
        if (c == 0) s0a += acc; else s1a += acc;
      }
    }
    s0a += __shfl_xor(s0a, 16, 64); s0a += __shfl_xor(s0a, 32, 64);
    s1a += __shfl_xor(s1a, 16, 64); s1a += __shfl_xor(s1a, 32, 64);
    if (lane < 16){
      out[(size_t)Btot*64 + r0 + n]      = -s0a;
      out[(size_t)Btot*64 + r0 + 16 + n] = -s1a;
    }
  }
}

extern "C" void kernel_launch(void* const* d_in, const int* in_sizes, int n_in,
                              void* d_out, int out_size, void* d_ws, size_t ws_size,
                              hipStream_t stream){
  const float* t  = (const float*)d_in[0];
  const float* z  = (const float*)d_in[1];
  const float* e  = (const float*)d_in[2];
  const float* W0 = (const float*)d_in[3];
  const float* b0 = (const float*)d_in[4];
  const float* W1 = (const float*)d_in[5];
  const float* b1 = (const float*)d_in[6];
  const float* W2 = (const float*)d_in[7];
  const float* b2 = (const float*)d_in[8];
  float* out = (float*)d_out;
  const long long B = (long long)in_sizes[1] / 64;   // 262144
  const int grid = (int)(B / RPB);                   // 512
  ode_fused<<<grid, 256, SMEM_BYTES, stream>>>(t, z, e, W0, b0, W1, b1, W2, b2, out, B);
}

// Round 5
// 208.909 us; speedup vs baseline: 1.3235x; 1.3235x over previous
//
#include <hip/hip_runtime.h>

typedef unsigned short u16;
typedef unsigned int   u32;
typedef __attribute__((ext_vector_type(4))) float  f32x4;
typedef __attribute__((ext_vector_type(8))) __bf16 bf16x8;

#define BLOCK 512
#define ITERS 2
#define RPB   (8*32*ITERS)      // 512 rows per block
#define HSTRF 68                // f32 transpose row stride (floats): 272B, bank-rotating
#define HSTRU 136               // u16 view of same stride
#define TBUF_F (16*HSTRF)       // 1088 floats per wave
#define SMEM_BYTES 109312       // 48K wf3 + 8K wf2 + 16K wb + 768 bias + 34816 tbuf -> 1 block/CU

__device__ __forceinline__ u32 pkbf(float a, float b){
  u16 ua = __builtin_bit_cast(u16, (__bf16)a);
  u16 ub = __builtin_bit_cast(u16, (__bf16)b);
  return (u32)ua | ((u32)ub << 16);
}
__device__ __forceinline__ u32 pk2(__bf16 a, __bf16 b){
  return (u32)__builtin_bit_cast(u16, a) | ((u32)__builtin_bit_cast(u16, b) << 16);
}
__device__ __forceinline__ bf16x8 ldfrag(const u16* base, int idx){
  return __builtin_bit_cast(bf16x8, *(const uint4*)(base + (size_t)idx * 8));
}
__device__ __forceinline__ bf16x8 cvt8(float4 a, float4 b){
  uint4 u;
  u.x = pkbf(a.x, a.y); u.y = pkbf(a.z, a.w);
  u.z = pkbf(b.x, b.y); u.w = pkbf(b.z, b.w);
  return __builtin_bit_cast(bf16x8, u);
}
__device__ __forceinline__ f32x4 mfma16(bf16x8 a, bf16x8 b, f32x4 c){
  return __builtin_amdgcn_mfma_f32_16x16x32_bf16(a, b, c, 0, 0, 0);
}
// exact 3-way bf16 split of 8 f32
__device__ __forceinline__ void split8(float4 a, float4 b, bf16x8* out){
  float x[8] = {a.x, a.y, a.z, a.w, b.x, b.y, b.z, b.w};
  bf16x8 l0, l1, l2;
  #pragma unroll
  for (int j = 0; j < 8; ++j){
    float v = x[j];
    __bf16 p0 = (__bf16)v; float r = v - (float)p0;
    __bf16 p1 = (__bf16)r; r = r - (float)p1;
    __bf16 p2 = (__bf16)r;
    l0[j] = p0; l1[j] = p1; l2[j] = p2;
  }
  out[0] = l0; out[1] = l1; out[2] = l2;
}
// hp layer: 3-level A (LDS) x 3-level B (regs), 6 significant terms; 2 col-sets share A-frags
__device__ __forceinline__ void hp_layer(const u16* w0, const u16* w1, const u16* w2,
    int lane, const bf16x8 Bv[2][2][3], f32x4 hout[2][4]){
  #pragma unroll
  for (int mt = 0; mt < 4; ++mt){
    const int f0 = (mt*2+0)*64 + lane, f1 = (mt*2+1)*64 + lane;
    bf16x8 A00 = ldfrag(w0, f0), A01 = ldfrag(w1, f0), A02 = ldfrag(w2, f0);
    bf16x8 A10 = ldfrag(w0, f1), A11 = ldfrag(w1, f1), A12 = ldfrag(w2, f1);
    #pragma unroll
    for (int c = 0; c < 2; ++c){
      f32x4 a = {0.f, 0.f, 0.f, 0.f};
      a = mfma16(A00, Bv[c][0][0], a);
      a = mfma16(A00, Bv[c][0][1], a);
      a = mfma16(A01, Bv[c][0][0], a);
      a = mfma16(A00, Bv[c][0][2], a);
      a = mfma16(A01, Bv[c][0][1], a);
      a = mfma16(A02, Bv[c][0][0], a);
      a = mfma16(A10, Bv[c][1][0], a);
      a = mfma16(A10, Bv[c][1][1], a);
      a = mfma16(A11, Bv[c][1][0], a);
      a = mfma16(A10, Bv[c][1][2], a);
      a = mfma16(A11, Bv[c][1][1], a);
      a = mfma16(A12, Bv[c][1][0], a);
      hout[c][mt] = a;
    }
  }
}

// M = feature dim (A = weights, LDS), N = batch (B = activations).
// A: A[m=lane&15][k=(lane>>4)*8+j]; C/D: n=lane&15, m=(lane>>4)*4+r.
__global__ __launch_bounds__(BLOCK, 2) void ode_fused(
    const float* __restrict__ tptr, const float* __restrict__ z, const float* __restrict__ e,
    const float* __restrict__ W0p, const float* __restrict__ b0p,
    const float* __restrict__ W1p, const float* __restrict__ b1p,
    const float* __restrict__ W2p, const float* __restrict__ b2p,
    float* __restrict__ out, long long Btot)
{
  extern __shared__ __align__(16) char smem[];
  u16*   wf3  = (u16*)smem;                 // [6][4096] fwd L0/L1 A-frags, 3 levels each
  u16*   wf2  = wf3 + 6*4096;               // [4096] fwd L2 A-frags
  u16*   wb   = wf2 + 4096;                 // [2][4096]: W1^T, W2^T bwd A-frags
  float* bias = (float*)(wb + 2*4096);      // [3][64]
  float* tbuf = bias + 192;                 // [8][TBUF_F] per-wave private transpose scratch

  const int tid = threadIdx.x;
  const int wave = tid >> 6, lane = tid & 63;
  const int n = lane & 15, q = lane >> 4;
  const float tf = tptr[0];
  const float* Ws[3] = {W0p, W1p, W2p};
  const float* bs[3] = {b0p, b1p, b2p};

  // ---- preload iter-0 z/e (overlaps weight staging) ----
  float4 zc[8], ec[8];
  {
    const int r0 = blockIdx.x*RPB + wave*32;
    const float4* zr0 = (const float4*)(z + (size_t)(r0 + n)*64);
    const float4* zr1 = (const float4*)(z + (size_t)(r0 + 16 + n)*64);
    zc[0]=zr0[2*q]; zc[1]=zr0[2*q+1]; zc[2]=zr0[8+2*q]; zc[3]=zr0[9+2*q];
    zc[4]=zr1[2*q]; zc[5]=zr1[2*q+1]; zc[6]=zr1[8+2*q]; zc[7]=zr1[9+2*q];
    const float4* er0 = (const float4*)(e + (size_t)(r0 + n)*64);
    const float4* er1 = (const float4*)(e + (size_t)(r0 + 16 + n)*64);
    ec[0]=er0[2*q]; ec[1]=er0[2*q+1]; ec[2]=er0[8+2*q]; ec[3]=er0[9+2*q];
    ec[4]=er1[2*q]; ec[5]=er1[2*q+1]; ec[6]=er1[8+2*q]; ec[7]=er1[9+2*q];
  }

  // ---- one-time weight staging ----
  for (int L = 0; L < 3; ++L){
    const float* W = Ws[L];
    for (int eidx = tid; eidx < 512; eidx += BLOCK){
      const int l = eidx & 63, km = eidx >> 6;
      const int mt = km >> 1, kc = km & 1;
      const int n15 = l & 15, qq = l >> 4;
      { // forward A[m][k] = W[m][k+1]
        const float* p = W + (mt*16 + n15)*65 + 1 + kc*32 + qq*8;
        if (L < 2){
          uint4 u0, u1, u2;
          u32* d0 = (u32*)&u0; u32* d1 = (u32*)&u1; u32* d2 = (u32*)&u2;
          #pragma unroll
          for (int h = 0; h < 4; ++h){
            __bf16 a0, a1, a2, c0, c1, c2;
            float v = p[2*h];
            a0 = (__bf16)v; float r = v - (float)a0;
            a1 = (__bf16)r; r = r - (float)a1; a2 = (__bf16)r;
            v = p[2*h+1];
            c0 = (__bf16)v; r = v - (float)c0;
            c1 = (__bf16)r; r = r - (float)c1; c2 = (__bf16)r;
            d0[h] = pk2(a0, c0); d1[h] = pk2(a1, c1); d2[h] = pk2(a2, c2);
          }
          *(uint4*)(&wf3[(L*3+0)*4096 + eidx*8]) = u0;
          *(uint4*)(&wf3[(L*3+1)*4096 + eidx*8]) = u1;
          *(uint4*)(&wf3[(L*3+2)*4096 + eidx*8]) = u2;
        } else {
          uint4 u;
          u.x = pkbf(p[0], p[1]); u.y = pkbf(p[2], p[3]);
          u.z = pkbf(p[4], p[5]); u.w = pkbf(p[6], p[7]);
          *(uint4*)(&wf2[eidx*8]) = u;
        }
      }
      if (L >= 1){ // backward A[m][k] = W[k][m+1]
        const float* p = W + (kc*32 + qq*8)*65 + mt*16 + n15 + 1;
        uint4 u;
        u.x = pkbf(p[0],   p[65]);  u.y = pkbf(p[130], p[195]);
        u.z = pkbf(p[260], p[325]); u.w = pkbf(p[390], p[455]);
        *(uint4*)(&wb[(L-1)*4096 + eidx*8]) = u;
      }
    }
  }
  if (tid < 192){
    const int L = tid >> 6, m = tid & 63;
    bias[L*64 + m] = bs[L][m] + tf * Ws[L][m*65];
  }
  __syncthreads();   // the only barrier

  float* tb  = tbuf + wave*TBUF_F;   // per-wave private: no barrier needed
  u16*  tbu  = (u16*)tb;

  for (int it = 0; it < ITERS; ++it){
    const int r0 = blockIdx.x*RPB + it*256 + wave*32;
    const size_t row0 = (size_t)(r0 + n);
    const size_t row1 = (size_t)(r0 + 16 + n);

    // ---- prefetch next iter z/e ----
    float4 zn[8], en[8];
    if (it + 1 < ITERS){
      const int r1 = r0 + 256;
      const float4* zr0 = (const float4*)(z + (size_t)(r1 + n)*64);
      const float4* zr1 = (const float4*)(z + (size_t)(r1 + 16 + n)*64);
      zn[0]=zr0[2*q]; zn[1]=zr0[2*q+1]; zn[2]=zr0[8+2*q]; zn[3]=zr0[9+2*q];
      zn[4]=zr1[2*q]; zn[5]=zr1[2*q+1]; zn[6]=zr1[8+2*q]; zn[7]=zr1[9+2*q];
      const float4* er0 = (const float4*)(e + (size_t)(r1 + n)*64);
      const float4* er1 = (const float4*)(e + (size_t)(r1 + 16 + n)*64);
      en[0]=er0[2*q]; en[1]=er0[2*q+1]; en[2]=er0[8+2*q]; en[3]=er0[9+2*q];
      en[4]=er1[2*q]; en[5]=er1[2*q+1]; en[6]=er1[8+2*q]; en[7]=er1[9+2*q];
    }

    // ---- split z; convert e early (frees f32 regs) ----
    bf16x8 zB[2][2][3];
    split8(zc[0], zc[1], &zB[0][0][0]);
    split8(zc[2], zc[3], &zB[0][1][0]);
    split8(zc[4], zc[5], &zB[1][0][0]);
    split8(zc[6], zc[7], &zB[1][1][0]);
    bf16x8 eB[2][2];
    eB[0][0] = cvt8(ec[0], ec[1]); eB[0][1] = cvt8(ec[2], ec[3]);
    eB[1][0] = cvt8(ec[4], ec[5]); eB[1][1] = cvt8(ec[6], ec[7]);

    // ---- L0 (hp) + relu + mask ----
    f32x4 h0[2][4];
    hp_layer(wf3 + 0*4096, wf3 + 1*4096, wf3 + 2*4096, lane, zB, h0);
    u32 mask0[2] = {0u, 0u};
    #pragma unroll
    for (int c = 0; c < 2; ++c)
      #pragma unroll
      for (int mt = 0; mt < 4; ++mt){
        const f32x4 bv = *(const f32x4*)(&bias[0*64 + mt*16 + q*4]);
        #pragma unroll
        for (int r = 0; r < 4; ++r){
          float v = h0[c][mt][r] + bv[r];
          bool pos = v > 0.f;
          h0[c][mt][r] = pos ? v : 0.f;
          mask0[c] |= (pos ? 1u : 0u) << (mt*4 + r);
        }
      }
    // C->B transpose via per-wave LDS (f32 fidelity), col-set at a time
    bf16x8 h0B[2][2][3];
    #pragma unroll
    for (int c = 0; c < 2; ++c){
      #pragma unroll
      for (int mt = 0; mt < 4; ++mt)
        *(float4*)(tb + n*HSTRF + mt*16 + q*4) = __builtin_bit_cast(float4, h0[c][mt]);
      const float* tr = tb + n*HSTRF;
      split8(*(const float4*)(tr + q*8),      *(const float4*)(tr + q*8 + 4),      &h0B[c][0][0]);
      split8(*(const float4*)(tr + 32 + q*8), *(const float4*)(tr + 32 + q*8 + 4), &h0B[c][1][0]);
    }

    // ---- L1 (hp) + relu + mask + pack ----
    f32x4 h1[2][4];
    hp_layer(wf3 + 3*4096, wf3 + 4*4096, wf3 + 5*4096, lane, h0B, h1);
    u32 mask1[2] = {0u, 0u};
    uint2 ph[2][4];
    #pragma unroll
    for (int c = 0; c < 2; ++c)
      #pragma unroll
      for (int mt = 0; mt < 4; ++mt){
        const f32x4 bv = *(const f32x4*)(&bias[1*64 + mt*16 + q*4]);
        float v0, v1, v2, v3;
        {
          float v = h1[c][mt][0] + bv[0]; bool p = v > 0.f; v0 = p ? v : 0.f; mask1[c] |= (p?1u:0u) << (mt*4+0);
        }
        { float v = h1[c][mt][1] + bv[1]; bool p = v > 0.f; v1 = p ? v : 0.f; mask1[c] |= (p?1u:0u) << (mt*4+1); }
        { float v = h1[c][mt][2] + bv[2]; bool p = v > 0.f; v2 = p ? v : 0.f; mask1[c] |= (p?1u:0u) << (mt*4+2); }
        { float v = h1[c][mt][3] + bv[3]; bool p = v > 0.f; v3 = p ? v : 0.f; mask1[c] |= (p?1u:0u) << (mt*4+3); }
        ph[c][mt].x = pkbf(v0, v1);
        ph[c][mt].y = pkbf(v2, v3);
      }
    bf16x8 h1B[2][2];
    #pragma unroll
    for (int c = 0; c < 2; ++c){
      #pragma unroll
      for (int mt = 0; mt < 4; ++mt)
        *(uint2*)(tbu + n*HSTRU + mt*16 + q*4) = ph[c][mt];
      const u16* tru = tbu + n*HSTRU;
      h1B[c][0] = __builtin_bit_cast(bf16x8, *(const uint4*)(tru + q*8));
      h1B[c][1] = __builtin_bit_cast(bf16x8, *(const uint4*)(tru + 32 + q*8));
    }

    // ---- L2 + store z_dot ----
    #pragma unroll
    for (int mt = 0; mt < 4; ++mt){
      bf16x8 A0 = ldfrag(wf2, (mt*2+0)*64 + lane);
      bf16x8 A1 = ldfrag(wf2, (mt*2+1)*64 + lane);
      const f32x4 bv = *(const f32x4*)(&bias[2*64 + mt*16 + q*4]);
      #pragma unroll
      for (int c = 0; c < 2; ++c){
        f32x4 a = {0.f, 0.f, 0.f, 0.f};
        a = mfma16(A0, h1B[c][0], a);
        a = mfma16(A1, h1B[c][1], a);
        float4 w;
        w.x = a[0] + bv[0]; w.y = a[1] + bv[1];
        w.z = a[2] + bv[2]; w.w = a[3] + bv[3];
        const size_t rr = (c == 0) ? row0 : row1;
        *(float4*)(out + rr*64 + mt*16 + q*4) = w;
      }
    }

    // ---- backward: g1 = (W2[:,1:]^T e) . mask1 ----
    uint2 pg[2][4];
    #pragma unroll
    for (int mt = 0; mt < 4; ++mt){
      bf16x8 A0 = ldfrag(wb + 4096, (mt*2+0)*64 + lane);
      bf16x8 A1 = ldfrag(wb + 4096, (mt*2+1)*64 + lane);
      #pragma unroll
      for (int c = 0; c < 2; ++c){
        f32x4 a = {0.f, 0.f, 0.f, 0.f};
        a = mfma16(A0, eB[c][0], a);
        a = mfma16(A1, eB[c][1], a);
        float v0 = ((mask1[c] >> (mt*4+0)) & 1u) ? a[0] : 0.f;
        float v1 = ((mask1[c] >> (mt*4+1)) & 1u) ? a[1] : 0.f;
        float v2 = ((mask1[c] >> (mt*4+2)) & 1u) ? a[2] : 0.f;
        float v3 = ((mask1[c] >> (mt*4+3)) & 1u) ? a[3] : 0.f;
        pg[c][mt].x = pkbf(v0, v1);
        pg[c][mt].y = pkbf(v2, v3);
      }
    }
    bf16x8 g1B[2][2];
    #pragma unroll
    for (int c = 0; c < 2; ++c){
      #pragma unroll
      for (int mt = 0; mt < 4; ++mt)
        *(uint2*)(tbu + n*HSTRU + mt*16 + q*4) = pg[c][mt];
      const u16* tru = tbu + n*HSTRU;
      g1B[c][0] = __builtin_bit_cast(bf16x8, *(const uint4*)(tru + q*8));
      g1B[c][1] = __builtin_bit_cast(bf16x8, *(const uint4*)(tru + 32 + q*8));
    }

    // ---- g0 = (W1[:,1:]^T g1) . mask0 ; u = W0[:,1:] e ; div = sum(g0*u) ----
    float s0 = 0.f, s1 = 0.f;
    #pragma unroll
    for (int mt = 0; mt < 4; ++mt){
      bf16x8 G0 = ldfrag(wb, (mt*2+0)*64 + lane);
      bf16x8 G1 = ldfrag(wb, (mt*2+1)*64 + lane);
      bf16x8 U0 = ldfrag(wf3, (mt*2+0)*64 + lane);
      bf16x8 U1 = ldfrag(wf3, (mt*2+1)*64 + lane);
      #pragma unroll
      for (int c = 0; c < 2; ++c){
        f32x4 g = {0.f, 0.f, 0.f, 0.f};
        g = mfma16(G0, g1B[c][0], g);
        g = mfma16(G1, g1B[c][1], g);
        f32x4 u = {0.f, 0.f, 0.f, 0.f};
        u = mfma16(U0, eB[c][0], u);
        u = mfma16(U1, eB[c][1], u);
        float acc = 0.f;
        #pragma unroll
        for (int r = 0; r < 4; ++r)
          acc += ((mask0[c] >> (mt*4+r)) & 1u) ? g[r]*u[r] : 0.f;
        if (c == 0) s0 += acc; else s1 += acc;
      }
    }
    s0 += __shfl_xor(s0, 16, 64); s0 += __shfl_xor(s0, 32, 64);
    s1 += __shfl_xor(s1, 16, 64); s1 += __shfl_xor(s1, 32, 64);
    {
      float dv = (lane < 16) ? -s0 : -s1;
      if (lane < 32)
        out[(size_t)Btot*64 + r0 + lane] = dv;   // lanes 16..31: r0+lane = r0+16+n
    }

    // ---- rotate prefetch ----
    if (it + 1 < ITERS){
      #pragma unroll
      for (int i = 0; i < 8; ++i){ zc[i] = zn[i]; ec[i] = en[i]; }
    }
  }
}

extern "C" void kernel_launch(void* const* d_in, const int* in_sizes, int n_in,
                              void* d_out, int out_size, void* d_ws, size_t ws_size,
                              hipStream_t stream){
  const float* t  = (const float*)d_in[0];
  const float* z  = (const float*)d_in[1];
  const float* e  = (const float*)d_in[2];
  const float* W0 = (const float*)d_in[3];
  const float* b0 = (const float*)d_in[4];
  const float* W1 = (const float*)d_in[5];
  const float* b1 = (const float*)d_in[6];
  const float* W2 = (const float*)d_in[7];
  const float* b2 = (const float*)d_in[8];
  float* out = (float*)d_out;
  const long long B = (long long)in_sizes[1] / 64;   // 262144
  const int grid = (int)(B / RPB);                   // 512
  ode_fused<<<grid, BLOCK, SMEM_BYTES, stream>>>(t, z, e, W0, b0, W1, b1, W2, b2, out, B);
}